// Round 10
// baseline (115.547 us; speedup 1.0000x reference)
//
#include <hip/hip_runtime.h>
#include <hip/hip_bf16.h>

typedef __attribute__((ext_vector_type(8))) short bf16x8s;   // 8 bf16 as shorts (MFMA frag)
typedef __attribute__((ext_vector_type(4))) float f32x4;
typedef __attribute__((ext_vector_type(16))) float f32x16;
typedef __attribute__((ext_vector_type(4))) __bf16 bf16x4;
typedef __attribute__((ext_vector_type(8))) __bf16 bf16x8;

typedef const __attribute__((address_space(1))) void gvoid_t;
typedef __attribute__((address_space(3))) void lvoid_t;

constexpr int Bc = 2, Tc = 2048, Dc = 1024, Hc = 16, HDc = 64;
constexpr int Mc = Bc * Tc;  // 4096

// ---------------- fused fp32 -> bf16 convert: x (4096 blocks) + 4 weights (4096) ----
__global__ void cvt_all(const float* __restrict__ x,
                        const float* __restrict__ wq, const float* __restrict__ wk,
                        const float* __restrict__ wv, const float* __restrict__ wp,
                        __bf16* __restrict__ xb, __bf16* __restrict__ wb) {
  const int bid = blockIdx.x;
  const float* src;
  __bf16* dst;
  int i;
  if (bid < 4096) {
    src = x; dst = xb; i = (bid * 256 + threadIdx.x) * 4;
  } else {
    const int r = bid - 4096;
    const int w = r >> 10;
    src = (w == 0) ? wq : (w == 1) ? wk : (w == 2) ? wv : wp;
    dst = wb + (size_t)w * (Dc * Dc);
    i = ((r & 1023) * 256 + threadIdx.x) * 4;
  }
  float4 v = *(const float4*)(src + i);
  bf16x4 o;
  o[0] = (__bf16)v.x; o[1] = (__bf16)v.y; o[2] = (__bf16)v.z; o[3] = (__bf16)v.w;
  *(bf16x4*)(dst + i) = o;
}

// ---------------- QKV GEMM: C[m][e] = sum_d A[m][d] * W[e][d] ----------------------
// z=0: RoPE+score-scale -> [B,H,T,HD]; z=1: RoPE -> [B,H,T,HD];
// z=2: V^T epilogue (LDS transpose bounce) -> vt [B,H,HD,T]
__launch_bounds__(256, 2)
__global__ void gemm_qkv(const __bf16* __restrict__ A,
                         const __bf16* __restrict__ W,
                         __bf16* __restrict__ outb,
                         __bf16* __restrict__ vtout,
                         const float* __restrict__ cbt,
                         const float* __restrict__ sbt) {
  __shared__ __bf16 smem[2][128 * 64];
  __bf16* Alds = smem[0];
  __bf16* Blds = smem[1];
  const int tid = threadIdx.x;
  const int lane = tid & 63, wid = tid >> 6;
  const int wr = wid >> 1, wc = wid & 1;
  const int lr = lane & 15, lg = lane >> 4;
  // XCD-chunked remap: each XCD owns 4 M-rows x 8 N-cols (1MB A + 2MB B in its L2)
  const int lid = blockIdx.x + (int)gridDim.x * blockIdx.y;
  const int xcd = lid & 7, g = lid >> 3;
  const int brow = (xcd * 4 + (g & 3)) * 128;
  const int bcol = (g >> 2) * 128;
  const __bf16* Wm = W + (size_t)blockIdx.z * (Dc * Dc);

  f32x4 acc[4][4] = {};

  const char* Ag = (const char*)(A + (size_t)brow * Dc);
  const char* Bg = (const char*)(Wm + (size_t)bcol * Dc);
  const int r0 = tid >> 3;
  const int cb = (tid & 7) * 16;

  for (int k0 = 0; k0 < Dc; k0 += 64) {
#pragma unroll
    for (int i = 0; i < 4; ++i) {
      const int r = i * 32 + r0;
      const int ldsoff = (i * 256 + wid * 64) * 16;
      __builtin_amdgcn_global_load_lds(
          (gvoid_t*)(Ag + (size_t)r * (Dc * 2) + k0 * 2 + cb),
          (lvoid_t*)((char*)Alds + ldsoff), 16, 0, 0);
      __builtin_amdgcn_global_load_lds(
          (gvoid_t*)(Bg + (size_t)r * (Dc * 2) + k0 * 2 + cb),
          (lvoid_t*)((char*)Blds + ldsoff), 16, 0, 0);
    }
    __syncthreads();
#pragma unroll
    for (int kk = 0; kk < 2; ++kk) {
      const int col = kk * 32 + lg * 8;
      bf16x8s af[4], bfv[4];
#pragma unroll
      for (int m = 0; m < 4; ++m)
        af[m] = *(const bf16x8s*)(Alds + (wr * 64 + m * 16 + lr) * 64 + col);
#pragma unroll
      for (int n = 0; n < 4; ++n)
        bfv[n] = *(const bf16x8s*)(Blds + (wc * 64 + n * 16 + lr) * 64 + col);
#pragma unroll
      for (int m = 0; m < 4; ++m)
#pragma unroll
        for (int n = 0; n < 4; ++n)
          acc[m][n] = __builtin_amdgcn_mfma_f32_16x16x32_bf16(af[m], bfv[n], acc[m][n], 0, 0, 0);
    }
    __syncthreads();
  }

  const int z = blockIdx.z;
  if (z == 2) {
    // V^T epilogue: stage C^T halves in LDS, coalesced store to vt [B,H,HD,T]
    const int bb = brow >> 11, t0b = brow & (Tc - 1);
    __bf16* tile_t = smem[0];  // [64][136]
#pragma unroll
    for (int h2 = 0; h2 < 2; ++h2) {
      __syncthreads();
      if (wc == h2) {
#pragma unroll
        for (int n = 0; n < 4; ++n) {
#pragma unroll
          for (int m = 0; m < 4; ++m) {
            bf16x4 pb;
#pragma unroll
            for (int j = 0; j < 4; ++j) pb[j] = (__bf16)acc[m][n][j];
            *(bf16x4*)(tile_t + (n * 16 + lr) * 136 + wr * 64 + m * 16 + lg * 4) = pb;
          }
        }
      }
      __syncthreads();
#pragma unroll
      for (int pass = 0; pass < 4; ++pass) {
        const int r = pass * 16 + (tid >> 4);
        const int c8 = (tid & 15) * 8;
        bf16x8 vvv = *(const bf16x8*)(tile_t + r * 136 + c8);
        const int gn = bcol + h2 * 64 + r;
        const int h = gn >> 6, hd = gn & 63;
        *(bf16x8*)(vtout + (((size_t)bb * Hc + h) * HDc + hd) * Tc + t0b + c8) = vvv;
      }
    }
    return;
  }

  // z==0/1: fused RoPE (+ score scale for Q), scatter to [B,H,T,HD]
  {
    const float scl = (z == 0) ? 0.18033688011112042f : 1.0f;  // (1/8)*log2(e)
#pragma unroll
    for (int m = 0; m < 4; ++m) {
#pragma unroll
      for (int j = 0; j < 4; ++j) {
        const int gm = brow + wr * 64 + m * 16 + lg * 4 + j;
        const float* cbase = cbt + (size_t)gm * HDc;
        const float* sbase = sbt + (size_t)gm * HDc;
#pragma unroll
        for (int n = 0; n < 2; ++n) {
          const int i = n * 16 + lr;
          const float c0 = cbase[i], s0 = sbase[i];
          const float c1 = cbase[i + 32], s1 = sbase[i + 32];
          const float v0 = acc[m][n][j], v1 = acc[m][n + 2][j];
          acc[m][n][j]     = (v0 * c0 - v1 * s0) * scl;
          acc[m][n + 2][j] = (v1 * c1 + v0 * s1) * scl;
        }
      }
    }
    __bf16* dst = outb + (size_t)z * ((size_t)Mc * Dc);
#pragma unroll
    for (int m = 0; m < 4; ++m) {
#pragma unroll
      for (int j = 0; j < 4; ++j) {
        const int gm = brow + wr * 64 + m * 16 + lg * 4 + j;
        const int bb = gm >> 11, t = gm & (Tc - 1);
#pragma unroll
        for (int n = 0; n < 4; ++n) {
          const int gn = bcol + wc * 64 + n * 16 + lr;
          const int h = gn >> 6, hd = gn & 63;
          dst[(((size_t)bb * Hc + h) * Tc + t) * HDc + hd] = (__bf16)acc[m][n][j];
        }
      }
    }
  }
}

// ---------------- output projection GEMM: 128x64 tiles, 512 blocks (2/CU) ----------
__launch_bounds__(256, 2)
__global__ void gemm_proj(const __bf16* __restrict__ A, const __bf16* __restrict__ W,
                          float* __restrict__ outf) {
  __shared__ __bf16 Alds[128 * 64];
  __shared__ __bf16 Blds[64 * 64];
  const int tid = threadIdx.x;
  const int lane = tid & 63, wid = tid >> 6;
  const int lr = lane & 15, lg = lane >> 4;
  const int lid = blockIdx.x + (int)gridDim.x * blockIdx.y;  // 512 blocks
  const int xcd = lid & 7, g = lid >> 3;
  const int brow = (xcd * 4 + (g & 3)) * 128;
  const int bcol = (g >> 2) * 64;
  f32x4 acc[2][4] = {};
  const char* Ag = (const char*)(A + (size_t)brow * Dc);
  const char* Bg = (const char*)(W + (size_t)bcol * Dc);
  const int r0 = tid >> 3;
  const int cb = (tid & 7) * 16;
  for (int k0 = 0; k0 < Dc; k0 += 64) {
#pragma unroll
    for (int i = 0; i < 4; ++i) {
      const int r = i * 32 + r0;
      const int ldsoff = (i * 256 + wid * 64) * 16;
      __builtin_amdgcn_global_load_lds(
          (gvoid_t*)(Ag + (size_t)r * (Dc * 2) + k0 * 2 + cb),
          (lvoid_t*)((char*)Alds + ldsoff), 16, 0, 0);
    }
#pragma unroll
    for (int i = 0; i < 2; ++i) {
      const int r = i * 32 + r0;
      const int ldsoff = (i * 256 + wid * 64) * 16;
      __builtin_amdgcn_global_load_lds(
          (gvoid_t*)(Bg + (size_t)r * (Dc * 2) + k0 * 2 + cb),
          (lvoid_t*)((char*)Blds + ldsoff), 16, 0, 0);
    }
    __syncthreads();
#pragma unroll
    for (int kk = 0; kk < 2; ++kk) {
      const int col = kk * 32 + lg * 8;
      bf16x8s af[2], bfv[4];
#pragma unroll
      for (int m = 0; m < 2; ++m)
        af[m] = *(const bf16x8s*)(Alds + (wid * 32 + m * 16 + lr) * 64 + col);
#pragma unroll
      for (int n = 0; n < 4; ++n)
        bfv[n] = *(const bf16x8s*)(Blds + (n * 16 + lr) * 64 + col);
#pragma unroll
      for (int m = 0; m < 2; ++m)
#pragma unroll
        for (int n = 0; n < 4; ++n)
          acc[m][n] = __builtin_amdgcn_mfma_f32_16x16x32_bf16(af[m], bfv[n], acc[m][n], 0, 0, 0);
    }
    __syncthreads();
  }
#pragma unroll
  for (int m = 0; m < 2; ++m)
#pragma unroll
    for (int j = 0; j < 4; ++j) {
      const int gm = brow + wid * 32 + m * 16 + lg * 4 + j;
#pragma unroll
      for (int n = 0; n < 4; ++n) {
        const int gn = bcol + n * 16 + lr;
        outf[(size_t)gm * Dc + gn] = acc[m][n][j];
      }
    }
}

// ---------------- causal flash attention (v10: 4-wave blocks, shared stage) --------
// 512 blocks (32 bh x 16 q-tiles of 128 rows) x 256 thr (4 waves). Each wave owns
// 32 q-cols; all 4 share one K/V LDS stage (staging per wave-unit halves vs v9).
// 2 blocks/CU (32KB LDS), 16 waves/CU = 4 waves/SIMD. Balanced pairing: qt flips
// with (pass^(pass>>1))&1 so the two blocks on a CU sum to exactly 34 units.
// Per-wave diagonal u_diag = 2qt + (wid>>1); waves skip compute after it.
// In-register P (cvt_pk + permlane32_swap), static-max softmax, per-lane l.
__launch_bounds__(256, 2)
__global__ void attn_kernel(const __bf16* __restrict__ Q, const __bf16* __restrict__ K,
                            const __bf16* __restrict__ Vt, __bf16* __restrict__ O) {
  __shared__ __bf16 Klds[2][64 * 64];   // [kv][hd] rows 128B, XOR-swizzled key kv&7
  __shared__ __bf16 Vlds[2][64 * 64];   // [hd][kv] rows 128B, XOR-swizzled key hd&7
  const int f = blockIdx.x;
  const int xcd = f & 7, g = f >> 3;    // 64 blocks per XCD = 4 bh x 16 q-tiles
  const int pass = g >> 4, g4 = g & 15;
  const int bh = xcd * 4 + pass;
  const int qt = ((pass ^ (pass >> 1)) & 1) ? (15 - g4) : g4;  // CU pairs {c,15-c}
  const int tid = threadIdx.x;
  const int lane = tid & 63, wid = tid >> 6;
  const int q31 = lane & 31, hh = lane >> 5;   // lane's q-col / k-half
  const int k3 = q31 & 7;                      // row-XOR swizzle key
  const __bf16* Qp = Q + (size_t)bh * Tc * HDc;
  const char* Kb = (const char*)(K + (size_t)bh * Tc * HDc);
  const char* Vb = (const char*)(Vt + (size_t)bh * HDc * Tc);

  const int units = 2 * qt + 2;
  const int u_diag = 2 * qt + (wid >> 1);      // this wave's diagonal unit

  // staging: 4 instrs/thread/unit (2 K + 2 V); instr i covers rows [i*32, i*32+32)
  // row = i*32 + wid*8 + (lane>>3), slot = lane&7, swizzle key row&7 = (lane>>3)&7
  const int sr8 = wid * 8 + (lane >> 3);
  const int sxor = ((lane & 7) ^ ((lane >> 3) & 7)) << 4;  // pre-swizzled src col
  const char* vsrc = Vb + (size_t)sr8 * (Tc * 2) + sxor;

  const int q0w = qt * 128 + wid * 32;
  bf16x8s qf[4];
#pragma unroll
  for (int ks = 0; ks < 4; ++ks)
    qf[ks] = *(const bf16x8s*)(Qp + (q0w + q31) * HDc + ks * 16 + hh * 8);

  const int b = bh >> 4, h = bh & 15;

  f32x16 acc0 = {}, acc1 = {};
  float lsum = 0.f;

#define STAGE(IT, BUF)                                                                   \
  do {                                                                                   \
    _Pragma("unroll")                                                                    \
    for (int i_ = 0; i_ < 2; ++i_) {                                                     \
      __builtin_amdgcn_global_load_lds(                                                  \
          (gvoid_t*)(Kb + (size_t)((IT) * 64 + i_ * 32 + sr8) * 128 + sxor),             \
          (lvoid_t*)((char*)Klds[BUF] + i_ * 4096 + wid * 1024), 16, 0, 0);              \
      __builtin_amdgcn_global_load_lds(                                                  \
          (gvoid_t*)(vsrc + (size_t)i_ * 32 * (Tc * 2) + (IT) * 128),                    \
          (lvoid_t*)((char*)Vlds[BUF] + i_ * 4096 + wid * 1024), 16, 0, 0);              \
    }                                                                                    \
  } while (0)

  STAGE(0, 0);
  asm volatile("s_waitcnt vmcnt(0)" ::: "memory");
  __builtin_amdgcn_sched_barrier(0);
  __builtin_amdgcn_s_barrier();
  __builtin_amdgcn_sched_barrier(0);

  for (int u = 0; u < units; ++u) {
    if (u + 1 < units) STAGE(u + 1, (u + 1) & 1);
    __builtin_amdgcn_sched_barrier(0);

    if (u <= u_diag) {  // wave-uniform: skip after own diagonal
      const int kv0 = u * 64;
      const char* Kl = (const char*)Klds[u & 1];
      const char* Vl = (const char*)Vlds[u & 1];
      const bool fin = (u == u_diag);
      const int thr = q0w + q31 - kv0 - 4 * hh;  // mask when 32ct+8qd+j > thr

      // ---- QK^T (swapped: D[kv][q], lane owns q-col) + static-max softmax ----
      unsigned w0[8], w1[8];
#pragma unroll
      for (int ct = 0; ct < 2; ++ct) {
        bf16x8s kf[4];
#pragma unroll
        for (int ks = 0; ks < 4; ++ks)
          kf[ks] = *(const bf16x8s*)(Kl + (ct * 32 + q31) * 128 + (((2 * ks + hh) ^ k3) << 4));
        f32x16 z = {};
        __builtin_amdgcn_s_setprio(1);
#pragma unroll
        for (int ks = 0; ks < 4; ++ks)
          z = __builtin_amdgcn_mfma_f32_32x32x16_bf16(kf[ks], qf[ks], z, 0, 0, 0);
        __builtin_amdgcn_s_setprio(0);
#pragma unroll
        for (int qd = 0; qd < 4; ++qd) {
          float e[4];
#pragma unroll
          for (int j = 0; j < 4; ++j) {
            float ev = __builtin_amdgcn_exp2f(z[qd * 4 + j]);
            if (fin && (ct * 32 + qd * 8 + j > thr)) ev = 0.f;
            lsum += ev;
            e[j] = ev;
          }
          const int n = ct * 4 + qd;
          asm("v_cvt_pk_bf16_f32 %0, %1, %2" : "=v"(w0[n]) : "v"(e[0]), "v"(e[1]));
          asm("v_cvt_pk_bf16_f32 %0, %1, %2" : "=v"(w1[n]) : "v"(e[2]), "v"(e[3]));
        }
      }

      // ---- assemble PV B-frags in registers (T12) ----
      bf16x8s pfr[4];
#pragma unroll
      for (int ks = 0; ks < 4; ++ks) {
        unsigned a = w0[2 * ks], bb2 = w0[2 * ks + 1];
        unsigned c = w1[2 * ks], d = w1[2 * ks + 1];
        asm volatile("v_permlane32_swap_b32 %0, %1" : "+v"(a), "+v"(bb2));
        asm volatile("v_permlane32_swap_b32 %0, %1" : "+v"(c), "+v"(d));
        union { unsigned u[4]; bf16x8s v; } uu;
        uu.u[0] = a; uu.u[1] = c; uu.u[2] = bb2; uu.u[3] = d;
        pfr[ks] = uu.v;
      }

      // ---- PV: D[hd][q] = Vt_frag x P_frag ----
      __builtin_amdgcn_s_setprio(1);
#pragma unroll
      for (int ks = 0; ks < 4; ++ks) {
        const int so = ((2 * ks + hh) ^ k3) << 4;
        const bf16x8s va0 = *(const bf16x8s*)(Vl + q31 * 128 + so);
        const bf16x8s va1 = *(const bf16x8s*)(Vl + (32 + q31) * 128 + so);
        acc0 = __builtin_amdgcn_mfma_f32_32x32x16_bf16(va0, pfr[ks], acc0, 0, 0, 0);
        acc1 = __builtin_amdgcn_mfma_f32_32x32x16_bf16(va1, pfr[ks], acc1, 0, 0, 0);
      }
      __builtin_amdgcn_s_setprio(0);
    }

    if (u + 1 < units) {
      asm volatile("s_waitcnt vmcnt(0)" ::: "memory");  // stage(u+1) landed
      __builtin_amdgcn_sched_barrier(0);
      __builtin_amdgcn_s_barrier();  // all waves done with buf[u&1]; buf[(u+1)&1] ready
      __builtin_amdgcn_sched_barrier(0);
    }
  }
#undef STAGE

  // finalize: l reduce across the two k-halves, scale, write O
  const float lt = lsum + __shfl_xor(lsum, 32);
  const float linv = 1.f / lt;
  const int t = q0w + q31;
  __bf16* dst = O + ((size_t)b * Tc + t) * Dc + h * HDc;
#pragma unroll
  for (int qd = 0; qd < 4; ++qd) {
    bf16x4 o0, o1;
#pragma unroll
    for (int j = 0; j < 4; ++j) {
      o0[j] = (__bf16)(acc0[qd * 4 + j] * linv);
      o1[j] = (__bf16)(acc1[qd * 4 + j] * linv);
    }
    *(bf16x4*)(dst + qd * 8 + hh * 4) = o0;
    *(bf16x4*)(dst + 32 + qd * 8 + hh * 4) = o1;
  }
}

// ---------------- launch ----------------
extern "C" void kernel_launch(void* const* d_in, const int* in_sizes, int n_in,
                              void* d_out, int out_size, void* d_ws, size_t ws_size,
                              hipStream_t stream) {
  const float* x   = (const float*)d_in[0];
  const float* cbt = (const float*)d_in[1];
  const float* sbt = (const float*)d_in[2];
  const float* Wq  = (const float*)d_in[3];
  const float* Wk  = (const float*)d_in[4];
  const float* Wv  = (const float*)d_in[5];
  const float* Wp  = (const float*)d_in[6];
  float* out = (float*)d_out;
  char* ws = (char*)d_ws;
  __bf16* xb = (__bf16*)(ws);
  __bf16* wb = (__bf16*)(ws + (8u << 20));
  __bf16* qb = (__bf16*)(ws + (16u << 20));
  __bf16* vt = (__bf16*)(ws + (40u << 20));
  __bf16* ao = (__bf16*)(ws + (48u << 20));
  __bf16* kb = qb + (size_t)Mc * Dc;

  cvt_all<<<8192, 256, 0, stream>>>(x, Wq, Wk, Wv, Wp, xb, wb);
  gemm_qkv<<<dim3(8, 32, 3), 256, 0, stream>>>(xb, wb, qb, vt, cbt, sbt);
  attn_kernel<<<512, 256, 0, stream>>>(qb, kb, vt, ao);
  gemm_proj<<<dim3(16, 32), 256, 0, stream>>>(ao, wb + 3u * (Dc * Dc), out);
}

// Round 11
// 99.876 us; speedup vs baseline: 1.1569x; 1.1569x over previous
//
#include <hip/hip_runtime.h>
#include <hip/hip_bf16.h>

typedef __attribute__((ext_vector_type(8))) short bf16x8s;   // 8 bf16 as shorts (MFMA frag)
typedef __attribute__((ext_vector_type(4))) float f32x4;
typedef __attribute__((ext_vector_type(16))) float f32x16;
typedef __attribute__((ext_vector_type(4))) __bf16 bf16x4;
typedef __attribute__((ext_vector_type(8))) __bf16 bf16x8;

typedef const __attribute__((address_space(1))) void gvoid_t;
typedef __attribute__((address_space(3))) void lvoid_t;

constexpr int Bc = 2, Tc = 2048, Dc = 1024, Hc = 16, HDc = 64;
constexpr int Mc = Bc * Tc;  // 4096

// ---------------- fused fp32 -> bf16 convert: x (4096 blocks) + 4 weights (4096) ----
__global__ void cvt_all(const float* __restrict__ x,
                        const float* __restrict__ wq, const float* __restrict__ wk,
                        const float* __restrict__ wv, const float* __restrict__ wp,
                        __bf16* __restrict__ xb, __bf16* __restrict__ wb) {
  const int bid = blockIdx.x;
  const float* src;
  __bf16* dst;
  int i;
  if (bid < 4096) {
    src = x; dst = xb; i = (bid * 256 + threadIdx.x) * 4;
  } else {
    const int r = bid - 4096;
    const int w = r >> 10;
    src = (w == 0) ? wq : (w == 1) ? wk : (w == 2) ? wv : wp;
    dst = wb + (size_t)w * (Dc * Dc);
    i = ((r & 1023) * 256 + threadIdx.x) * 4;
  }
  float4 v = *(const float4*)(src + i);
  bf16x4 o;
  o[0] = (__bf16)v.x; o[1] = (__bf16)v.y; o[2] = (__bf16)v.z; o[3] = (__bf16)v.w;
  *(bf16x4*)(dst + i) = o;
}

// ---------------- QKV GEMM: C[m][e] = sum_d A[m][d] * W[e][d] ----------------------
// z=0: RoPE+score-scale -> [B,H,T,HD]; z=1: RoPE -> [B,H,T,HD];
// z=2: V^T epilogue (LDS transpose bounce) -> vt [B,H,HD,T]
__launch_bounds__(256, 2)
__global__ void gemm_qkv(const __bf16* __restrict__ A,
                         const __bf16* __restrict__ W,
                         __bf16* __restrict__ outb,
                         __bf16* __restrict__ vtout,
                         const float* __restrict__ cbt,
                         const float* __restrict__ sbt) {
  __shared__ __bf16 smem[2][128 * 64];
  __bf16* Alds = smem[0];
  __bf16* Blds = smem[1];
  const int tid = threadIdx.x;
  const int lane = tid & 63, wid = tid >> 6;
  const int wr = wid >> 1, wc = wid & 1;
  const int lr = lane & 15, lg = lane >> 4;
  // XCD-chunked remap: each XCD owns 4 M-rows x 8 N-cols (1MB A + 2MB B in its L2)
  const int lid = blockIdx.x + (int)gridDim.x * blockIdx.y;
  const int xcd = lid & 7, g = lid >> 3;
  const int brow = (xcd * 4 + (g & 3)) * 128;
  const int bcol = (g >> 2) * 128;
  const __bf16* Wm = W + (size_t)blockIdx.z * (Dc * Dc);

  f32x4 acc[4][4] = {};

  const char* Ag = (const char*)(A + (size_t)brow * Dc);
  const char* Bg = (const char*)(Wm + (size_t)bcol * Dc);
  const int r0 = tid >> 3;
  const int cb = (tid & 7) * 16;

  for (int k0 = 0; k0 < Dc; k0 += 64) {
#pragma unroll
    for (int i = 0; i < 4; ++i) {
      const int r = i * 32 + r0;
      const int ldsoff = (i * 256 + wid * 64) * 16;
      __builtin_amdgcn_global_load_lds(
          (gvoid_t*)(Ag + (size_t)r * (Dc * 2) + k0 * 2 + cb),
          (lvoid_t*)((char*)Alds + ldsoff), 16, 0, 0);
      __builtin_amdgcn_global_load_lds(
          (gvoid_t*)(Bg + (size_t)r * (Dc * 2) + k0 * 2 + cb),
          (lvoid_t*)((char*)Blds + ldsoff), 16, 0, 0);
    }
    __syncthreads();
#pragma unroll
    for (int kk = 0; kk < 2; ++kk) {
      const int col = kk * 32 + lg * 8;
      bf16x8s af[4], bfv[4];
#pragma unroll
      for (int m = 0; m < 4; ++m)
        af[m] = *(const bf16x8s*)(Alds + (wr * 64 + m * 16 + lr) * 64 + col);
#pragma unroll
      for (int n = 0; n < 4; ++n)
        bfv[n] = *(const bf16x8s*)(Blds + (wc * 64 + n * 16 + lr) * 64 + col);
#pragma unroll
      for (int m = 0; m < 4; ++m)
#pragma unroll
        for (int n = 0; n < 4; ++n)
          acc[m][n] = __builtin_amdgcn_mfma_f32_16x16x32_bf16(af[m], bfv[n], acc[m][n], 0, 0, 0);
    }
    __syncthreads();
  }

  const int z = blockIdx.z;
  if (z == 2) {
    // V^T epilogue: stage C^T halves in LDS, coalesced store to vt [B,H,HD,T]
    const int bb = brow >> 11, t0b = brow & (Tc - 1);
    __bf16* tile_t = smem[0];  // [64][136]
#pragma unroll
    for (int h2 = 0; h2 < 2; ++h2) {
      __syncthreads();
      if (wc == h2) {
#pragma unroll
        for (int n = 0; n < 4; ++n) {
#pragma unroll
          for (int m = 0; m < 4; ++m) {
            bf16x4 pb;
#pragma unroll
            for (int j = 0; j < 4; ++j) pb[j] = (__bf16)acc[m][n][j];
            *(bf16x4*)(tile_t + (n * 16 + lr) * 136 + wr * 64 + m * 16 + lg * 4) = pb;
          }
        }
      }
      __syncthreads();
#pragma unroll
      for (int pass = 0; pass < 4; ++pass) {
        const int r = pass * 16 + (tid >> 4);
        const int c8 = (tid & 15) * 8;
        bf16x8 vvv = *(const bf16x8*)(tile_t + r * 136 + c8);
        const int gn = bcol + h2 * 64 + r;
        const int h = gn >> 6, hd = gn & 63;
        *(bf16x8*)(vtout + (((size_t)bb * Hc + h) * HDc + hd) * Tc + t0b + c8) = vvv;
      }
    }
    return;
  }

  // z==0/1: fused RoPE (+ score scale for Q), scatter to [B,H,T,HD]
  {
    const float scl = (z == 0) ? 0.18033688011112042f : 1.0f;  // (1/8)*log2(e)
#pragma unroll
    for (int m = 0; m < 4; ++m) {
#pragma unroll
      for (int j = 0; j < 4; ++j) {
        const int gm = brow + wr * 64 + m * 16 + lg * 4 + j;
        const float* cbase = cbt + (size_t)gm * HDc;
        const float* sbase = sbt + (size_t)gm * HDc;
#pragma unroll
        for (int n = 0; n < 2; ++n) {
          const int i = n * 16 + lr;
          const float c0 = cbase[i], s0 = sbase[i];
          const float c1 = cbase[i + 32], s1 = sbase[i + 32];
          const float v0 = acc[m][n][j], v1 = acc[m][n + 2][j];
          acc[m][n][j]     = (v0 * c0 - v1 * s0) * scl;
          acc[m][n + 2][j] = (v1 * c1 + v0 * s1) * scl;
        }
      }
    }
    __bf16* dst = outb + (size_t)z * ((size_t)Mc * Dc);
#pragma unroll
    for (int m = 0; m < 4; ++m) {
#pragma unroll
      for (int j = 0; j < 4; ++j) {
        const int gm = brow + wr * 64 + m * 16 + lg * 4 + j;
        const int bb = gm >> 11, t = gm & (Tc - 1);
#pragma unroll
        for (int n = 0; n < 4; ++n) {
          const int gn = bcol + wc * 64 + n * 16 + lr;
          const int h = gn >> 6, hd = gn & 63;
          dst[(((size_t)bb * Hc + h) * Tc + t) * HDc + hd] = (__bf16)acc[m][n][j];
        }
      }
    }
  }
}

// ---------------- output projection GEMM: 128x64 tiles, 512 blocks (2/CU) ----------
__launch_bounds__(256, 2)
__global__ void gemm_proj(const __bf16* __restrict__ A, const __bf16* __restrict__ W,
                          float* __restrict__ outf) {
  __shared__ __bf16 Alds[128 * 64];
  __shared__ __bf16 Blds[64 * 64];
  const int tid = threadIdx.x;
  const int lane = tid & 63, wid = tid >> 6;
  const int lr = lane & 15, lg = lane >> 4;
  const int lid = blockIdx.x + (int)gridDim.x * blockIdx.y;  // 512 blocks
  const int xcd = lid & 7, g = lid >> 3;
  const int brow = (xcd * 4 + (g & 3)) * 128;
  const int bcol = (g >> 2) * 64;
  f32x4 acc[2][4] = {};
  const char* Ag = (const char*)(A + (size_t)brow * Dc);
  const char* Bg = (const char*)(W + (size_t)bcol * Dc);
  const int r0 = tid >> 3;
  const int cb = (tid & 7) * 16;
  for (int k0 = 0; k0 < Dc; k0 += 64) {
#pragma unroll
    for (int i = 0; i < 4; ++i) {
      const int r = i * 32 + r0;
      const int ldsoff = (i * 256 + wid * 64) * 16;
      __builtin_amdgcn_global_load_lds(
          (gvoid_t*)(Ag + (size_t)r * (Dc * 2) + k0 * 2 + cb),
          (lvoid_t*)((char*)Alds + ldsoff), 16, 0, 0);
    }
#pragma unroll
    for (int i = 0; i < 2; ++i) {
      const int r = i * 32 + r0;
      const int ldsoff = (i * 256 + wid * 64) * 16;
      __builtin_amdgcn_global_load_lds(
          (gvoid_t*)(Bg + (size_t)r * (Dc * 2) + k0 * 2 + cb),
          (lvoid_t*)((char*)Blds + ldsoff), 16, 0, 0);
    }
    __syncthreads();
#pragma unroll
    for (int kk = 0; kk < 2; ++kk) {
      const int col = kk * 32 + lg * 8;
      bf16x8s af[2], bfv[4];
#pragma unroll
      for (int m = 0; m < 2; ++m)
        af[m] = *(const bf16x8s*)(Alds + (wid * 32 + m * 16 + lr) * 64 + col);
#pragma unroll
      for (int n = 0; n < 4; ++n)
        bfv[n] = *(const bf16x8s*)(Blds + (n * 16 + lr) * 64 + col);
#pragma unroll
      for (int m = 0; m < 2; ++m)
#pragma unroll
        for (int n = 0; n < 4; ++n)
          acc[m][n] = __builtin_amdgcn_mfma_f32_16x16x32_bf16(af[m], bfv[n], acc[m][n], 0, 0, 0);
    }
    __syncthreads();
  }
#pragma unroll
  for (int m = 0; m < 2; ++m)
#pragma unroll
    for (int j = 0; j < 4; ++j) {
      const int gm = brow + wid * 32 + m * 16 + lg * 4 + j;
#pragma unroll
      for (int n = 0; n < 4; ++n) {
        const int gn = bcol + n * 16 + lr;
        outf[(size_t)gm * Dc + gn] = acc[m][n][j];
      }
    }
}

// ---------------- causal flash attention (v11: 4 waves = 2 q-halves x 2 kv-halves) --
// 1024 blocks (32 bh x 32 q-tiles of 64 rows, v9's proven balanced map) x 256 thr.
// Wave (qh, kp): q-cols [qt*64+qh*32, +32), kv sub-tile [u*64+kp*32, +32) of each
// unit. 4096 waves = 16/CU = 4 waves/SIMD (vs v9's 2) with the SAME 66 units/CU
// balance. K/V staged once per 4 waves. Static-max softmax => partial (acc, l)
// are additive: kp-pairs merge once at the end via LDS (dead K/V buffers).
// Diagonal unit u==qt: wave(0,1) fully masked -> skips; (0,0),(1,1) mask; (1,0) full.
__launch_bounds__(256, 4)
__global__ void attn_kernel(const __bf16* __restrict__ Q, const __bf16* __restrict__ K,
                            const __bf16* __restrict__ Vt, __bf16* __restrict__ O) {
  __shared__ __bf16 Klds[2][64 * 64];   // [kv][hd] rows 128B, XOR-swizzled key kv&7
  __shared__ __bf16 Vlds[2][64 * 64];   // [hd][kv] rows 128B, XOR-swizzled key hd&7
  const int f = blockIdx.x;
  const int xcd = f & 7, g = f >> 3;    // 128 blocks per XCD = 4 bh x 32 q-tiles
  const int pass = g >> 5, g5 = g & 31;
  const int bh = xcd * 4 + pass;
  const int qt = (pass & 1) ? (31 - g5) : g5;  // CU (stride-32 round-robin) gets {c,31-c,c,31-c}
  const int tid = threadIdx.x;
  const int lane = tid & 63, wid = tid >> 6;
  const int qh = wid >> 1, kp = wid & 1;       // wave's q-half / kv-half
  const int q31 = lane & 31, hh = lane >> 5;   // lane's q-col / k(hd)-half
  const int k3 = q31 & 7;                      // row-XOR swizzle key
  const __bf16* Qp = Q + (size_t)bh * Tc * HDc;
  const char* Kb = (const char*)(K + (size_t)bh * Tc * HDc);
  const char* Vb = (const char*)(Vt + (size_t)bh * HDc * Tc);

  const int units = qt + 1;

  // staging (4 waves cooperatively): instr i covers rows [i*32, +32)
  const int sr8 = wid * 8 + (lane >> 3);
  const int sxor = ((lane & 7) ^ ((lane >> 3) & 7)) << 4;  // pre-swizzled src col
  const char* vsrc = Vb + (size_t)sr8 * (Tc * 2) + sxor;

  const int q0w = qt * 64 + qh * 32;
  bf16x8s qf[4];
#pragma unroll
  for (int ks = 0; ks < 4; ++ks)
    qf[ks] = *(const bf16x8s*)(Qp + (q0w + q31) * HDc + ks * 16 + hh * 8);

  const int b = bh >> 4, h = bh & 15;

  f32x16 acc0 = {}, acc1 = {};
  float lsum = 0.f;

#define STAGE(IT, BUF)                                                                   \
  do {                                                                                   \
    _Pragma("unroll")                                                                    \
    for (int i_ = 0; i_ < 2; ++i_) {                                                     \
      __builtin_amdgcn_global_load_lds(                                                  \
          (gvoid_t*)(Kb + (size_t)((IT) * 64 + i_ * 32 + sr8) * 128 + sxor),             \
          (lvoid_t*)((char*)Klds[BUF] + i_ * 4096 + wid * 1024), 16, 0, 0);              \
      __builtin_amdgcn_global_load_lds(                                                  \
          (gvoid_t*)(vsrc + (size_t)i_ * 32 * (Tc * 2) + (IT) * 128),                    \
          (lvoid_t*)((char*)Vlds[BUF] + i_ * 4096 + wid * 1024), 16, 0, 0);              \
    }                                                                                    \
  } while (0)

  STAGE(0, 0);
  asm volatile("s_waitcnt vmcnt(0)" ::: "memory");
  __builtin_amdgcn_sched_barrier(0);
  __builtin_amdgcn_s_barrier();
  __builtin_amdgcn_sched_barrier(0);

  for (int u = 0; u < units; ++u) {
    if (u + 1 < units) STAGE(u + 1, (u + 1) & 1);
    __builtin_amdgcn_sched_barrier(0);

    const bool last = (u == qt);
    if (!last || qh == 1 || kp == 0) {  // wave(0,1) fully masked on diagonal
      const char* Kl = (const char*)Klds[u & 1];
      const char* Vl = (const char*)Vlds[u & 1];
      const bool fin = last && (qh == kp);        // diagonal waves (0,0),(1,1)
      const int thr = q0w + q31 - u * 64 - kp * 32 - 4 * hh;  // mask when 8n+j > thr

      // ---- QK^T (swapped: D[kv][q], lane owns q-col) over the wave's 32-kv half ----
      bf16x8s kf[4];
#pragma unroll
      for (int ks = 0; ks < 4; ++ks)
        kf[ks] = *(const bf16x8s*)(Kl + (kp * 32 + q31) * 128 + (((2 * ks + hh) ^ k3) << 4));
      f32x16 z = {};
      __builtin_amdgcn_s_setprio(1);
#pragma unroll
      for (int ks = 0; ks < 4; ++ks)
        z = __builtin_amdgcn_mfma_f32_32x32x16_bf16(kf[ks], qf[ks], z, 0, 0, 0);
      __builtin_amdgcn_s_setprio(0);

      // ---- static-max softmax + pack ----
      unsigned w0[4], w1[4];
#pragma unroll
      for (int n = 0; n < 4; ++n) {
        float e[4];
#pragma unroll
        for (int j = 0; j < 4; ++j) {
          float ev = __builtin_amdgcn_exp2f(z[n * 4 + j]);
          if (fin && (n * 8 + j > thr)) ev = 0.f;
          lsum += ev;
          e[j] = ev;
        }
        asm("v_cvt_pk_bf16_f32 %0, %1, %2" : "=v"(w0[n]) : "v"(e[0]), "v"(e[1]));
        asm("v_cvt_pk_bf16_f32 %0, %1, %2" : "=v"(w1[n]) : "v"(e[2]), "v"(e[3]));
      }

      // ---- assemble PV B-frags in registers (T12) ----
      bf16x8s pfr[2];
#pragma unroll
      for (int ks2 = 0; ks2 < 2; ++ks2) {
        unsigned a = w0[2 * ks2], bb2 = w0[2 * ks2 + 1];
        unsigned c = w1[2 * ks2], d = w1[2 * ks2 + 1];
        asm volatile("v_permlane32_swap_b32 %0, %1" : "+v"(a), "+v"(bb2));
        asm volatile("v_permlane32_swap_b32 %0, %1" : "+v"(c), "+v"(d));
        union { unsigned u[4]; bf16x8s v; } uu;
        uu.u[0] = a; uu.u[1] = c; uu.u[2] = bb2; uu.u[3] = d;
        pfr[ks2] = uu.v;
      }

      // ---- PV over the wave's 32-kv half: D[hd][q] ----
      __builtin_amdgcn_s_setprio(1);
#pragma unroll
      for (int ks2 = 0; ks2 < 2; ++ks2) {
        const int so = ((kp * 4 + 2 * ks2 + hh) ^ k3) << 4;
        const bf16x8s va0 = *(const bf16x8s*)(Vl + q31 * 128 + so);
        const bf16x8s va1 = *(const bf16x8s*)(Vl + (32 + q31) * 128 + so);
        acc0 = __builtin_amdgcn_mfma_f32_32x32x16_bf16(va0, pfr[ks2], acc0, 0, 0, 0);
        acc1 = __builtin_amdgcn_mfma_f32_32x32x16_bf16(va1, pfr[ks2], acc1, 0, 0, 0);
      }
      __builtin_amdgcn_s_setprio(0);
    }

    if (u + 1 < units) {
      asm volatile("s_waitcnt vmcnt(0)" ::: "memory");  // stage(u+1) landed
      __builtin_amdgcn_sched_barrier(0);
      __builtin_amdgcn_s_barrier();  // all waves done with buf[u&1]; buf[(u+1)&1] ready
      __builtin_amdgcn_sched_barrier(0);
    }
  }
#undef STAGE

  // ---- kp-pair combine (static max => additive), then finalize ----
  __syncthreads();  // all K/V reads done; buffers become scratch
  float* tp = (qh == 0) ? (float*)(&Klds[0][0]) : (float*)(&Vlds[0][0]);
  if (kp == 1) {
#pragma unroll
    for (int i = 0; i < 16; ++i) {
      tp[i * 64 + lane] = acc0[i];
      tp[1024 + i * 64 + lane] = acc1[i];
    }
    tp[2048 + lane] = lsum;
  }
  __syncthreads();
  if (kp == 0) {
#pragma unroll
    for (int i = 0; i < 16; ++i) {
      acc0[i] += tp[i * 64 + lane];
      acc1[i] += tp[1024 + i * 64 + lane];
    }
    lsum += tp[2048 + lane];
    const float lt = lsum + __shfl_xor(lsum, 32);
    const float linv = 1.f / lt;
    const int t = q0w + q31;
    __bf16* dst = O + ((size_t)b * Tc + t) * Dc + h * HDc;
#pragma unroll
    for (int qd = 0; qd < 4; ++qd) {
      bf16x4 o0, o1;
#pragma unroll
      for (int j = 0; j < 4; ++j) {
        o0[j] = (__bf16)(acc0[qd * 4 + j] * linv);
        o1[j] = (__bf16)(acc1[qd * 4 + j] * linv);
      }
      *(bf16x4*)(dst + qd * 8 + hh * 4) = o0;
      *(bf16x4*)(dst + 32 + qd * 8 + hh * 4) = o1;
    }
  }
}

// ---------------- launch ----------------
extern "C" void kernel_launch(void* const* d_in, const int* in_sizes, int n_in,
                              void* d_out, int out_size, void* d_ws, size_t ws_size,
                              hipStream_t stream) {
  const float* x   = (const float*)d_in[0];
  const float* cbt = (const float*)d_in[1];
  const float* sbt = (const float*)d_in[2];
  const float* Wq  = (const float*)d_in[3];
  const float* Wk  = (const float*)d_in[4];
  const float* Wv  = (const float*)d_in[5];
  const float* Wp  = (const float*)d_in[6];
  float* out = (float*)d_out;
  char* ws = (char*)d_ws;
  __bf16* xb = (__bf16*)(ws);
  __bf16* wb = (__bf16*)(ws + (8u << 20));
  __bf16* qb = (__bf16*)(ws + (16u << 20));
  __bf16* vt = (__bf16*)(ws + (40u << 20));
  __bf16* ao = (__bf16*)(ws + (48u << 20));
  __bf16* kb = qb + (size_t)Mc * Dc;

  cvt_all<<<8192, 256, 0, stream>>>(x, Wq, Wk, Wv, Wp, xb, wb);
  gemm_qkv<<<dim3(8, 32, 3), 256, 0, stream>>>(xb, wb, qb, vt, cbt, sbt);
  attn_kernel<<<1024, 256, 0, stream>>>(qb, kb, vt, ao);
  gemm_proj<<<dim3(16, 32), 256, 0, stream>>>(ao, wb + 3u * (Dc * Dc), out);
}